// Round 11
// baseline (604.330 us; speedup 1.0000x reference)
//
#include <hip/hip_runtime.h>

// GeneralizedInteractionNet on MI355X (gfx950). R11: fused 3-layer kernel
// with EXPLICIT register double-buffering of per-n fragments.
//
// Per layer:  M[n,D,d] = W[n,D,d]*h[n,d]
//   GEMM1: C[i,D] = sum_d Bi[b,i,d] * M[n,D,d]
//   GEMM2: R[i,D] = sum_f AT[n,i,f] * B0T[b,D,f]^T
//   out[b,n,D] = sum_i C[i,D]*R[i,D]
// i padded 40->64 (2 row tiles of 32); f padded 40->48 (3 K-steps of 16).
// Padding garbage annihilated by exact zeros in AT (rows i>=40, cols f>=40).
//
// R10 post-mortem: VGPR_Count=112 == exactly the single-iter live set; the
// compiler allocated ZERO overlap headroom -> each n-iter's 14 L1/L2 loads
// are consumed serially (~2200 cyc exposed per 896-cyc MFMA iter),
// MfmaUtil 31%. R11: unroll n-loop x2 with two named fragment buffer sets;
// loads for n+1 issue before n's MFMA block and are consumed one full
// iteration later (~900 cyc of MFMA covers ~120-250 cyc L1/L2 latency).
// Regs: aBi 32 + bT 24 + 2x56 buffers + temps ~= 190 VGPR + 64 AGPR <= 256
// @ (128,2). Wave owns one b through all 3 layers; intermediate in private
// LDS patch (in-wave dep only -> zero barriers); 2 launches total.

typedef __bf16 bf16x8 __attribute__((ext_vector_type(8)));
typedef float  f32x16 __attribute__((ext_vector_type(16)));
typedef unsigned short us4 __attribute__((ext_vector_type(4)));

constexpr int BATCH = 2048;
constexpr int FDIM  = 40;
constexpr int DDIM  = 64;
constexpr int LAY   = 3;
constexpr int IPAD  = 64;   // i padded: 2 row-tiles of 32
constexpr int FPAD  = 48;   // f padded: 3 K-steps of 16
constexpr int LROW  = 72;   // LDS transpose row stride (elems); 144 B rows

__device__ __forceinline__ unsigned short f2bf(float f) {
  union { float f; unsigned u; } v; v.f = f;
  unsigned r = v.u + 0x7fff + ((v.u >> 16) & 1);   // round-to-nearest-even
  return (unsigned short)(r >> 16);
}

// Vectorized prep (4 elems/thread, ushort4 writes):
//  M[l,n,D,d]  = W*h (bf16, natural layout)
//  AT[l,n,i64,f48] = alpha[l,f,i,n], zero-padded (i>=40 or f>=40 -> 0)
//  B0b[b,f,d]  = bf16(inputs)          (layer-0 A operand)
//  B0T[b,d,f48]= bf16(inputs[b,f,d]), f>=40 -> 0   (GEMM2 B operand)
__global__ void prep_k(const float* __restrict__ W, const float* __restrict__ h,
                       const float* __restrict__ alpha, const float* __restrict__ inputs,
                       unsigned short* __restrict__ M, unsigned short* __restrict__ AT,
                       unsigned short* __restrict__ B0b, unsigned short* __restrict__ B0T) {
  int j = blockIdx.x * blockDim.x + threadIdx.x;
  const int nM4 = LAY * FDIM * DDIM * DDIM / 4;    // 122880
  const int nA4 = LAY * FDIM * IPAD * FPAD / 4;    // 92160
  const int nB4 = BATCH * FDIM * DDIM / 4;         // 1310720
  const int nT4 = BATCH * DDIM * FPAD / 4;         // 1572864
  if (j < nM4) {
    int e  = j * 4;
    int d  = e & 63;
    int ln = e >> 12;
    float4 wv = *reinterpret_cast<const float4*>(W + e);
    float4 hv = *reinterpret_cast<const float4*>(h + ln * DDIM + d);
    us4 o = { f2bf(wv.x * hv.x), f2bf(wv.y * hv.y), f2bf(wv.z * hv.z), f2bf(wv.w * hv.w) };
    *reinterpret_cast<us4*>(M + e) = o;
    return;
  }
  j -= nM4;
  if (j < nA4) {
    int e  = j * 4;
    int f  = e % FPAD;
    int ii = (e / FPAD) % IPAD;
    int n  = (e / (FPAD * IPAD)) % FDIM;
    int l  = e / (FPAD * IPAD * FDIM);
    us4 o = {0, 0, 0, 0};
    if (ii < FDIM) {
#pragma unroll
      for (int k = 0; k < 4; ++k)
        if (f + k < FDIM)
          o[k] = f2bf(alpha[(((size_t)l * FDIM + f + k) * FDIM + ii) * FDIM + n]);
    }
    *reinterpret_cast<us4*>(AT + e) = o;
    return;
  }
  j -= nA4;
  if (j < nB4) {
    int e = j * 4;
    float4 v = *reinterpret_cast<const float4*>(inputs + e);
    us4 o = { f2bf(v.x), f2bf(v.y), f2bf(v.z), f2bf(v.w) };
    *reinterpret_cast<us4*>(B0b + e) = o;
    return;
  }
  j -= nB4;
  if (j >= nT4) return;
  {
    int e  = j * 4;
    int f  = e % FPAD;
    int d  = (e / FPAD) % DDIM;
    int b  = e / (FPAD * DDIM);
    us4 o = {0, 0, 0, 0};
#pragma unroll
    for (int k = 0; k < 4; ++k)
      if (f + k < FDIM)
        o[k] = f2bf(inputs[((size_t)b * FDIM + f + k) * DDIM + d]);
    *reinterpret_cast<us4*>(B0T + e) = o;
  }
}

// mfma_f32_32x32x16_bf16 conventions:
//   A[m=lane&31][k=8*(lane>>5)+j]  B[k=8*(lane>>5)+j][col=lane&31]
//   C/D: col=lane&31, row=(reg&3)+8*(reg>>2)+4*(lane>>5)   [HW-verified]
__global__ __launch_bounds__(128, 2) void fused_k(
    const unsigned short* __restrict__ B0b,  // bf16 [B][40][64]
    const unsigned short* __restrict__ B0T,  // bf16 [B][64][48]
    const unsigned short* __restrict__ Mt,   // [3][40][64][64] bf16
    const unsigned short* __restrict__ ATt,  // [3][40][64][48] bf16 zero-padded
    float* __restrict__ outp)                // f32 [B][40][64]
{
  // Per-wave private transpose patch; in-wave dependency only -> NO barriers.
  __shared__ __align__(16) unsigned short xpose[2][FDIM * LROW];

  const int tid  = threadIdx.x;
  const int lane = tid & 63;
  const int w    = tid >> 6;                  // wave in block (0,1)
  const int c    = lane & 31;
  const int h    = lane >> 5;
  const int b    = blockIdx.x * 2 + w;        // this wave's batch element
  unsigned short* myL = xpose[w];

  // bT[dt][ks]: GEMM2 B = B0T[b][D][f] -- constant across ALL layers and n.
  bf16x8 bT[2][3];
#pragma unroll
  for (int dt = 0; dt < 2; ++dt)
#pragma unroll
    for (int ks = 0; ks < 3; ++ks)
      bT[dt][ks] = *reinterpret_cast<const bf16x8*>(
          B0T + ((size_t)b * DDIM + dt * 32 + c) * FPAD + ks * 16 + h * 8);

  // aBi[it][ks]: GEMM1 A for the current layer; layer 0 from global B0b.
  // Rows >=40 clamped to 39 (finite; killed by AT zero rows in aR).
  bf16x8 aBi[2][4];
#pragma unroll
  for (int it = 0; it < 2; ++it) {
    int row = it * 32 + c; if (row > FDIM - 1) row = FDIM - 1;
#pragma unroll
    for (int ks = 0; ks < 4; ++ks)
      aBi[it][ks] = *reinterpret_cast<const bf16x8*>(
          B0b + ((size_t)b * FDIM + row) * DDIM + ks * 16 + h * 8);
  }

  for (int l = 0; l < LAY; ++l) {
    const unsigned short* Ml = Mt  + l * (FDIM * DDIM * DDIM);
    const unsigned short* Al = ATt + l * (FDIM * IPAD * FPAD);

    if (l > 0) {
      // Refill aBi from the wave's LDS patch (prev layer's output,
      // transposed: row i, cols d contiguous). 8 ds_read_b128, once/layer.
#pragma unroll
      for (int it = 0; it < 2; ++it) {
        int row = it * 32 + c; if (row > FDIM - 1) row = FDIM - 1;
#pragma unroll
        for (int ks = 0; ks < 4; ++ks)
          aBi[it][ks] = *reinterpret_cast<const bf16x8*>(
              (const char*)myL + row * (LROW * 2) + ks * 32 + h * 16);
      }
    }

    // Two named fragment buffer sets for register double-buffering.
    bf16x8 mb0[2][4], at0[2][3], mb1[2][4], at1[2][3];

    auto loadf = [&](int n, bf16x8 (&mb)[2][4], bf16x8 (&at)[2][3]) {
      const unsigned short* Mn = Ml + n * (DDIM * DDIM);
      const unsigned short* An = Al + n * (IPAD * FPAD);
#pragma unroll
      for (int dt = 0; dt < 2; ++dt)
#pragma unroll
        for (int ks = 0; ks < 4; ++ks)
          mb[dt][ks] = *reinterpret_cast<const bf16x8*>(
              Mn + (dt * 32 + c) * DDIM + ks * 16 + h * 8);
#pragma unroll
      for (int it = 0; it < 2; ++it)
#pragma unroll
        for (int ks = 0; ks < 3; ++ks)
          at[it][ks] = *reinterpret_cast<const bf16x8*>(
              An + (it * 32 + c) * FPAD + ks * 16 + h * 8);
    };

    auto compute = [&](int n, const bf16x8 (&mb)[2][4], const bf16x8 (&at)[2][3]) {
      float pout[2] = {0.f, 0.f};   // [dt]
#pragma unroll
      for (int it = 0; it < 2; ++it) {
        f32x16 aC0 = {0,0,0,0,0,0,0,0,0,0,0,0,0,0,0,0};
        f32x16 aC1 = {0,0,0,0,0,0,0,0,0,0,0,0,0,0,0,0};
        f32x16 aR0 = {0,0,0,0,0,0,0,0,0,0,0,0,0,0,0,0};
        f32x16 aR1 = {0,0,0,0,0,0,0,0,0,0,0,0,0,0,0,0};
#pragma unroll
        for (int ks = 0; ks < 4; ++ks) {
          aC0 = __builtin_amdgcn_mfma_f32_32x32x16_bf16(aBi[it][ks], mb[0][ks], aC0, 0, 0, 0);
          aC1 = __builtin_amdgcn_mfma_f32_32x32x16_bf16(aBi[it][ks], mb[1][ks], aC1, 0, 0, 0);
        }
#pragma unroll
        for (int ks = 0; ks < 3; ++ks) {
          aR0 = __builtin_amdgcn_mfma_f32_32x32x16_bf16(at[it][ks], bT[0][ks], aR0, 0, 0, 0);
          aR1 = __builtin_amdgcn_mfma_f32_32x32x16_bf16(at[it][ks], bT[1][ks], aR1, 0, 0, 0);
        }
        {
          float t0 = 0.f, t1 = 0.f, t2 = 0.f, t3 = 0.f;
#pragma unroll
          for (int r = 0; r < 4; ++r) {
            t0 += aC0[r] * aR0[r];         t1 += aC0[r + 4] * aR0[r + 4];
            t2 += aC0[r + 8] * aR0[r + 8]; t3 += aC0[r + 12] * aR0[r + 12];
          }
          pout[0] += (t0 + t1) + (t2 + t3);
        }
        {
          float t0 = 0.f, t1 = 0.f, t2 = 0.f, t3 = 0.f;
#pragma unroll
          for (int r = 0; r < 4; ++r) {
            t0 += aC1[r] * aR1[r];         t1 += aC1[r + 4] * aR1[r + 4];
            t2 += aC1[r + 8] * aR1[r + 8]; t3 += aC1[r + 12] * aR1[r + 12];
          }
          pout[1] += (t0 + t1) + (t2 + t3);
        }
      }
      // Finish i-sum across lane halves; lane's value is D = lane.
      float v0 = pout[0] + __shfl_xor(pout[0], 32, 64);
      float v1 = pout[1] + __shfl_xor(pout[1], 32, 64);
      float val = h ? v1 : v0;
      if (l == LAY - 1) outp[((size_t)b * FDIM + n) * DDIM + lane] = val;
      else              myL[n * LROW + lane] = f2bf(val);  // 2 lanes/bank: free
    };

    // Software pipeline, unroll x2 (compile-time buffer selection).
    loadf(0, mb0, at0);
    for (int nn = 0; nn < FDIM / 2; ++nn) {
      const int n = 2 * nn;
      loadf(n + 1, mb1, at1);          // in flight during compute(n)
      compute(n, mb0, at0);
      if (n + 2 < FDIM) loadf(n + 2, mb0, at0);   // in flight during n+1
      compute(n + 1, mb1, at1);
    }
  }
}

extern "C" void kernel_launch(void* const* d_in, const int* in_sizes, int n_in,
                              void* d_out, int out_size, void* d_ws, size_t ws_size,
                              hipStream_t stream) {
  const float* inputs = (const float*)d_in[0];  // [2048,40,64]
  const float* W      = (const float*)d_in[1];  // [3,40,64,64]
  const float* alpha  = (const float*)d_in[2];  // [3,40,40,40]
  const float* h      = (const float*)d_in[3];  // [3,40,64,1]

  char* ws = (char*)d_ws;
  const size_t S   = (size_t)BATCH * FDIM * DDIM * 2;   // 10.49 MB B0b
  const size_t ST  = (size_t)BATCH * DDIM * FPAD * 2;   // 12.58 MB B0T
  unsigned short* B0b = (unsigned short*)(ws);
  unsigned short* B0T = (unsigned short*)(ws + S);
  unsigned short* Mb  = (unsigned short*)(ws + S + ST);
  unsigned short* ATb = (unsigned short*)(ws + S + ST + (size_t)LAY * FDIM * DDIM * DDIM * 2);

  const int nPrep4 = (LAY * FDIM * DDIM * DDIM + LAY * FDIM * IPAD * FPAD
                    + BATCH * FDIM * DDIM + BATCH * DDIM * FPAD) / 4;
  prep_k<<<(nPrep4 + 255) / 256, 256, 0, stream>>>(W, h, alpha, inputs, Mb, ATb, B0b, B0T);

  fused_k<<<dim3(BATCH / 2), dim3(128), 0, stream>>>(B0b, B0T, Mb, ATb, (float*)d_out);
}

// Round 12
// 320.175 us; speedup vs baseline: 1.8875x; 1.8875x over previous
//
#include <hip/hip_runtime.h>

// GeneralizedInteractionNet on MI355X (gfx950). R12: 1 wave/SIMD with the
// FULL 512-register file; wave owns 2 batch elements through all 3 layers.
//
// Per layer:  M[n,D,d] = W[n,D,d]*h[n,d]
//   GEMM1: C[i,D] = sum_d Bi[b,i,d] * M[n,D,d]
//   GEMM2: R[i,D] = sum_f AT[n,i,f] * B0T[b,D,f]^T
//   out[b,n,D] = sum_i C[i,D]*R[i,D]
// i padded 40->64 (2 row tiles of 32); f padded 40->48 (3 K-steps of 16).
// Padding garbage annihilated by exact zeros in AT (rows i>=40, cols f>=40).
//
// Register-wall history: full working set ~190 regs; +dbuf ~250. Every
// multi-wave budget either spills (R2/R6/R8/R11 — at (128,2) the compiler
// caps arch VGPRs at 128 and scratches the rest) or forces per-iter operand
// reloads (R9/R10, MfmaUtil 31-46%). R12 takes the unexplored corner:
// __launch_bounds__(64,1) -> 512 regs/wave. bT 48 + aBi 64 + dbuf frags 112
// + acc 128 (8 interleaved chains: 2b x {C,R} x 2dt) + temps ~= 390 << 512.
// Grid 1024 = 1 wave/SIMD exactly; wave is self-sufficient: zero barriers,
// zero reloads, n+1 fragments in flight during n's 56-MFMA block (452 cyc
// matrix-pipe window vs ~150 issue-cycles of other work). Pipe floor for
// the fused kernel: 6720 MFMA/wave x 8.07 cyc = 22.6 us.

typedef __bf16 bf16x8 __attribute__((ext_vector_type(8)));
typedef float  f32x16 __attribute__((ext_vector_type(16)));
typedef unsigned short us4 __attribute__((ext_vector_type(4)));

constexpr int BATCH = 2048;
constexpr int FDIM  = 40;
constexpr int DDIM  = 64;
constexpr int LAY   = 3;
constexpr int IPAD  = 64;   // i padded: 2 row-tiles of 32
constexpr int FPAD  = 48;   // f padded: 3 K-steps of 16
constexpr int LROW  = 72;   // LDS transpose row stride (elems); 144 B rows

__device__ __forceinline__ unsigned short f2bf(float f) {
  union { float f; unsigned u; } v; v.f = f;
  unsigned r = v.u + 0x7fff + ((v.u >> 16) & 1);   // round-to-nearest-even
  return (unsigned short)(r >> 16);
}

// Vectorized prep (4 elems/thread, ushort4 writes):
//  M[l,n,D,d]  = W*h (bf16, natural layout)
//  AT[l,n,i64,f48] = alpha[l,f,i,n], zero-padded (i>=40 or f>=40 -> 0)
//  B0b[b,f,d]  = bf16(inputs)          (layer-0 A operand)
//  B0T[b,d,f48]= bf16(inputs[b,f,d]), f>=40 -> 0   (GEMM2 B operand)
__global__ void prep_k(const float* __restrict__ W, const float* __restrict__ h,
                       const float* __restrict__ alpha, const float* __restrict__ inputs,
                       unsigned short* __restrict__ M, unsigned short* __restrict__ AT,
                       unsigned short* __restrict__ B0b, unsigned short* __restrict__ B0T) {
  int j = blockIdx.x * blockDim.x + threadIdx.x;
  const int nM4 = LAY * FDIM * DDIM * DDIM / 4;    // 122880
  const int nA4 = LAY * FDIM * IPAD * FPAD / 4;    // 92160
  const int nB4 = BATCH * FDIM * DDIM / 4;         // 1310720
  const int nT4 = BATCH * DDIM * FPAD / 4;         // 1572864
  if (j < nM4) {
    int e  = j * 4;
    int d  = e & 63;
    int ln = e >> 12;
    float4 wv = *reinterpret_cast<const float4*>(W + e);
    float4 hv = *reinterpret_cast<const float4*>(h + ln * DDIM + d);
    us4 o = { f2bf(wv.x * hv.x), f2bf(wv.y * hv.y), f2bf(wv.z * hv.z), f2bf(wv.w * hv.w) };
    *reinterpret_cast<us4*>(M + e) = o;
    return;
  }
  j -= nM4;
  if (j < nA4) {
    int e  = j * 4;
    int f  = e % FPAD;
    int ii = (e / FPAD) % IPAD;
    int n  = (e / (FPAD * IPAD)) % FDIM;
    int l  = e / (FPAD * IPAD * FDIM);
    us4 o = {0, 0, 0, 0};
    if (ii < FDIM) {
#pragma unroll
      for (int k = 0; k < 4; ++k)
        if (f + k < FDIM)
          o[k] = f2bf(alpha[(((size_t)l * FDIM + f + k) * FDIM + ii) * FDIM + n]);
    }
    *reinterpret_cast<us4*>(AT + e) = o;
    return;
  }
  j -= nA4;
  if (j < nB4) {
    int e = j * 4;
    float4 v = *reinterpret_cast<const float4*>(inputs + e);
    us4 o = { f2bf(v.x), f2bf(v.y), f2bf(v.z), f2bf(v.w) };
    *reinterpret_cast<us4*>(B0b + e) = o;
    return;
  }
  j -= nB4;
  if (j >= nT4) return;
  {
    int e  = j * 4;
    int f  = e % FPAD;
    int d  = (e / FPAD) % DDIM;
    int b  = e / (FPAD * DDIM);
    us4 o = {0, 0, 0, 0};
#pragma unroll
    for (int k = 0; k < 4; ++k)
      if (f + k < FDIM)
        o[k] = f2bf(inputs[((size_t)b * FDIM + f + k) * DDIM + d]);
    *reinterpret_cast<us4*>(B0T + e) = o;
  }
}

// mfma_f32_32x32x16_bf16 conventions:
//   A[m=lane&31][k=8*(lane>>5)+j]  B[k=8*(lane>>5)+j][col=lane&31]
//   C/D: col=lane&31, row=(reg&3)+8*(reg>>2)+4*(lane>>5)   [HW-verified]
__global__ __launch_bounds__(64, 1) void fused_k(
    const unsigned short* __restrict__ B0b,  // bf16 [B][40][64]
    const unsigned short* __restrict__ B0T,  // bf16 [B][64][48]
    const unsigned short* __restrict__ Mt,   // [3][40][64][64] bf16
    const unsigned short* __restrict__ ATt,  // [3][40][64][48] bf16 zero-padded
    float* __restrict__ outp)                // f32 [B][40][64]
{
  // Per-b private transpose patches; single wave per block -> NO barriers.
  __shared__ __align__(16) unsigned short xpose[2][FDIM * LROW];

  const int lane = threadIdx.x & 63;
  const int c    = lane & 31;
  const int h    = lane >> 5;
  const int b0   = blockIdx.x * 2;            // wave owns b0, b0+1

  // bT[b2][dt][ks]: GEMM2 B = B0T[b][D][f] -- constant across layers and n.
  bf16x8 bT[2][2][3];
#pragma unroll
  for (int b2 = 0; b2 < 2; ++b2)
#pragma unroll
    for (int dt = 0; dt < 2; ++dt)
#pragma unroll
      for (int ks = 0; ks < 3; ++ks)
        bT[b2][dt][ks] = *reinterpret_cast<const bf16x8*>(
            B0T + ((size_t)(b0 + b2) * DDIM + dt * 32 + c) * FPAD + ks * 16 + h * 8);

  // aBi[b2][it][ks]: GEMM1 A for the current layer; layer 0 from global B0b.
  // Rows >=40 clamped to 39 (finite; killed by AT zero rows in aR).
  bf16x8 aBi[2][2][4];
#pragma unroll
  for (int b2 = 0; b2 < 2; ++b2)
#pragma unroll
    for (int it = 0; it < 2; ++it) {
      int row = it * 32 + c; if (row > FDIM - 1) row = FDIM - 1;
#pragma unroll
      for (int ks = 0; ks < 4; ++ks)
        aBi[b2][it][ks] = *reinterpret_cast<const bf16x8*>(
            B0b + ((size_t)(b0 + b2) * FDIM + row) * DDIM + ks * 16 + h * 8);
    }

  for (int l = 0; l < LAY; ++l) {
    const unsigned short* Ml = Mt  + l * (FDIM * DDIM * DDIM);
    const unsigned short* Al = ATt + l * (FDIM * IPAD * FPAD);

    if (l > 0) {
      // Refill aBi from the wave's LDS patches (prev layer output,
      // transposed: row i, cols d contiguous). 16 ds_read_b128, once/layer.
#pragma unroll
      for (int b2 = 0; b2 < 2; ++b2)
#pragma unroll
        for (int it = 0; it < 2; ++it) {
          int row = it * 32 + c; if (row > FDIM - 1) row = FDIM - 1;
#pragma unroll
          for (int ks = 0; ks < 4; ++ks)
            aBi[b2][it][ks] = *reinterpret_cast<const bf16x8*>(
                (const char*)xpose[b2] + row * (LROW * 2) + ks * 32 + h * 16);
        }
    }

    // Two named fragment buffer sets (shared across both b) for register
    // double-buffering: n+1's 14 loads fly during n's 56-MFMA block.
    bf16x8 mb0[2][4], at0[2][3], mb1[2][4], at1[2][3];

    auto loadf = [&](int n, bf16x8 (&mb)[2][4], bf16x8 (&at)[2][3]) {
      const unsigned short* Mn = Ml + n * (DDIM * DDIM);
      const unsigned short* An = Al + n * (IPAD * FPAD);
#pragma unroll
      for (int dt = 0; dt < 2; ++dt)
#pragma unroll
        for (int ks = 0; ks < 4; ++ks)
          mb[dt][ks] = *reinterpret_cast<const bf16x8*>(
              Mn + (dt * 32 + c) * DDIM + ks * 16 + h * 8);
#pragma unroll
      for (int it = 0; it < 2; ++it)
#pragma unroll
        for (int ks = 0; ks < 3; ++ks)
          at[it][ks] = *reinterpret_cast<const bf16x8*>(
              An + (it * 32 + c) * FPAD + ks * 16 + h * 8);
    };

    auto compute = [&](int n, const bf16x8 (&mb)[2][4], const bf16x8 (&at)[2][3]) {
      float pout[2][2] = {{0.f, 0.f}, {0.f, 0.f}};   // [b2][dt]
#pragma unroll
      for (int it = 0; it < 2; ++it) {
        // 8 independent MFMA chains: [b2][dt] for C and R.
        f32x16 aC[2][2], aR[2][2];
#pragma unroll
        for (int b2 = 0; b2 < 2; ++b2)
#pragma unroll
          for (int dt = 0; dt < 2; ++dt) {
            aC[b2][dt] = (f32x16){0,0,0,0,0,0,0,0,0,0,0,0,0,0,0,0};
            aR[b2][dt] = (f32x16){0,0,0,0,0,0,0,0,0,0,0,0,0,0,0,0};
          }
#pragma unroll
        for (int ks = 0; ks < 4; ++ks)
#pragma unroll
          for (int b2 = 0; b2 < 2; ++b2)
#pragma unroll
            for (int dt = 0; dt < 2; ++dt)
              aC[b2][dt] = __builtin_amdgcn_mfma_f32_32x32x16_bf16(
                  aBi[b2][it][ks], mb[dt][ks], aC[b2][dt], 0, 0, 0);
#pragma unroll
        for (int ks = 0; ks < 3; ++ks)
#pragma unroll
          for (int b2 = 0; b2 < 2; ++b2)
#pragma unroll
            for (int dt = 0; dt < 2; ++dt)
              aR[b2][dt] = __builtin_amdgcn_mfma_f32_32x32x16_bf16(
                  at[it][ks], bT[b2][dt][ks], aR[b2][dt], 0, 0, 0);
        // Combine: per (b2,dt), 4 independent partial chains (depth 4).
#pragma unroll
        for (int b2 = 0; b2 < 2; ++b2)
#pragma unroll
          for (int dt = 0; dt < 2; ++dt) {
            float t0 = 0.f, t1 = 0.f, t2 = 0.f, t3 = 0.f;
#pragma unroll
            for (int r = 0; r < 4; ++r) {
              t0 += aC[b2][dt][r]      * aR[b2][dt][r];
              t1 += aC[b2][dt][r + 4]  * aR[b2][dt][r + 4];
              t2 += aC[b2][dt][r + 8]  * aR[b2][dt][r + 8];
              t3 += aC[b2][dt][r + 12] * aR[b2][dt][r + 12];
            }
            pout[b2][dt] += (t0 + t1) + (t2 + t3);
          }
      }
      // Finish i-sum across lane halves; lane's value is D = lane.
#pragma unroll
      for (int b2 = 0; b2 < 2; ++b2) {
        float v0 = pout[b2][0] + __shfl_xor(pout[b2][0], 32, 64);
        float v1 = pout[b2][1] + __shfl_xor(pout[b2][1], 32, 64);
        float val = h ? v1 : v0;
        if (l == LAY - 1)
          outp[((size_t)(b0 + b2) * FDIM + n) * DDIM + lane] = val;
        else
          xpose[b2][n * LROW + lane] = f2bf(val);   // 2 lanes/bank: free
      }
    };

    // Software pipeline, unroll x2 (compile-time buffer selection).
    loadf(0, mb0, at0);
    for (int nn = 0; nn < FDIM / 2; ++nn) {
      const int n = 2 * nn;
      loadf(n + 1, mb1, at1);                     // in flight during compute(n)
      compute(n, mb0, at0);
      if (n + 2 < FDIM) loadf(n + 2, mb0, at0);   // in flight during n+1
      compute(n + 1, mb1, at1);
    }
  }
}

extern "C" void kernel_launch(void* const* d_in, const int* in_sizes, int n_in,
                              void* d_out, int out_size, void* d_ws, size_t ws_size,
                              hipStream_t stream) {
  const float* inputs = (const float*)d_in[0];  // [2048,40,64]
  const float* W      = (const float*)d_in[1];  // [3,40,64,64]
  const float* alpha  = (const float*)d_in[2];  // [3,40,40,40]
  const float* h      = (const float*)d_in[3];  // [3,40,64,1]

  char* ws = (char*)d_ws;
  const size_t S   = (size_t)BATCH * FDIM * DDIM * 2;   // 10.49 MB B0b
  const size_t ST  = (size_t)BATCH * DDIM * FPAD * 2;   // 12.58 MB B0T
  unsigned short* B0b = (unsigned short*)(ws);
  unsigned short* B0T = (unsigned short*)(ws + S);
  unsigned short* Mb  = (unsigned short*)(ws + S + ST);
  unsigned short* ATb = (unsigned short*)(ws + S + ST + (size_t)LAY * FDIM * DDIM * DDIM * 2);

  const int nPrep4 = (LAY * FDIM * DDIM * DDIM + LAY * FDIM * IPAD * FPAD
                    + BATCH * FDIM * DDIM + BATCH * DDIM * FPAD) / 4;
  prep_k<<<(nPrep4 + 255) / 256, 256, 0, stream>>>(W, h, alpha, inputs, Mb, ATb, B0b, B0T);

  fused_k<<<dim3(BATCH / 2), dim3(64), 0, stream>>>(B0b, B0T, Mb, ATb, (float*)d_out);
}